// Round 4
// baseline (301.204 us; speedup 1.0000x reference)
//
#include <hip/hip_runtime.h>
#include <hip/hip_bf16.h>

typedef __bf16 bf16_t;
typedef __bf16 bf16x8 __attribute__((ext_vector_type(8)));
typedef float f32x4 __attribute__((ext_vector_type(4)));

#define M_TOK 128
#define K_IN 4096
#define N_OUT 11008
#define R_LORA 16
#define SCALING 2.0f
#define NSTRIPS 344  // 32-col strips
#define OCOLS 32
#define WSTRIDE 72  // bf16 elems per o-row in LDS (144 B, 16B-aligned, odd quads)

// ---------------------------------------------------------------------------
// Kernel A: x (fp32) -> xf (bf16, MFMA-A-fragment-contiguous layout) in ws,
// and T = (x @ lora_A^T) * SCALING in ws.
// xf layout: slot(mt, ks, lane) holds 8 bf16 where mt=m>>4, ks=k>>5,
//   lane=((k>>3)&3)*16 + (m&15), j=k&7.  In k_main the A-frag for (mt,ks)
//   is ONE contiguous 1 KB wave read (16 B/lane), L2-resident.
// ---------------------------------------------------------------------------
__global__ __launch_bounds__(256) void k_prep(const float* __restrict__ x,
                                              const float* __restrict__ loraA,
                                              float* __restrict__ T,
                                              bf16_t* __restrict__ xf) {
  const int m = blockIdx.x;
  const int mt = m >> 4;
  const int ml = m & 15;
  __shared__ float xs[K_IN];
  const float4* xr = (const float4*)(x + (size_t)m * K_IN);
#pragma unroll
  for (int c0 = 0; c0 < 2; ++c0) {
    const int c = c0 * 256 + threadIdx.x;  // c = k>>3, 0..511
    float4 vA = xr[2 * c], vB = xr[2 * c + 1];
    ((float4*)xs)[2 * c] = vA;
    ((float4*)xs)[2 * c + 1] = vB;
    bf16x8 pv = {(bf16_t)vA.x, (bf16_t)vA.y, (bf16_t)vA.z, (bf16_t)vA.w,
                 (bf16_t)vB.x, (bf16_t)vB.y, (bf16_t)vB.z, (bf16_t)vB.w};
    const int ks = c >> 2;
    const int lq = (c & 3) * 16 + ml;
    *(bf16x8*)(xf + ((size_t)(mt * 128 + ks) * 64 + lq) * 8) = pv;
  }
  __syncthreads();
  const int w = threadIdx.x >> 6;
  const int lane = threadIdx.x & 63;
  float a0 = 0.f, a1 = 0.f, a2 = 0.f, a3 = 0.f;
  const float4* A0 = (const float4*)(loraA + (size_t)(w * 4 + 0) * K_IN);
  const float4* A1 = (const float4*)(loraA + (size_t)(w * 4 + 1) * K_IN);
  const float4* A2 = (const float4*)(loraA + (size_t)(w * 4 + 2) * K_IN);
  const float4* A3 = (const float4*)(loraA + (size_t)(w * 4 + 3) * K_IN);
  for (int i = lane; i < K_IN / 4; i += 64) {
    float4 xv = ((float4*)xs)[i];
    float4 v0 = A0[i], v1 = A1[i], v2 = A2[i], v3 = A3[i];
    a0 += xv.x * v0.x + xv.y * v0.y + xv.z * v0.z + xv.w * v0.w;
    a1 += xv.x * v1.x + xv.y * v1.y + xv.z * v1.z + xv.w * v1.w;
    a2 += xv.x * v2.x + xv.y * v2.y + xv.z * v2.z + xv.w * v2.w;
    a3 += xv.x * v3.x + xv.y * v3.y + xv.z * v3.z + xv.w * v3.w;
  }
#pragma unroll
  for (int off = 32; off; off >>= 1) {
    a0 += __shfl_down(a0, off);
    a1 += __shfl_down(a1, off);
    a2 += __shfl_down(a2, off);
    a3 += __shfl_down(a3, off);
  }
  if (lane == 0) {
    float* tm = T + m * R_LORA + w * 4;
    tm[0] = a0 * SCALING;
    tm[1] = a1 * SCALING;
    tm[2] = a2 * SCALING;
    tm[3] = a3 * SCALING;
  }
}

// ---------------------------------------------------------------------------
// Kernel B: out = T @ lora_B^T (full overwrite of d_out -> handles poison,
// and provides the base the dequant GEMM atomically accumulates onto).
// ---------------------------------------------------------------------------
__global__ __launch_bounds__(256) void k_lora(const float* __restrict__ T,
                                              const float* __restrict__ loraB,
                                              float* __restrict__ out) {
  const int b = blockIdx.x;
  const int m = b / 43;
  const int o = (b % 43) * 256 + threadIdx.x;
  const float* t = T + m * R_LORA;
  const float4* br = (const float4*)(loraB + (size_t)o * R_LORA);
  float4 b0 = br[0], b1 = br[1], b2 = br[2], b3 = br[3];
  float s = t[0] * b0.x + t[1] * b0.y + t[2] * b0.z + t[3] * b0.w +
            t[4] * b1.x + t[5] * b1.y + t[6] * b1.z + t[7] * b1.w +
            t[8] * b2.x + t[9] * b2.y + t[10] * b2.z + t[11] * b2.w +
            t[12] * b3.x + t[13] * b3.y + t[14] * b3.z + t[15] * b3.w;
  out[(size_t)m * N_OUT + o] = s;
}

// ---------------------------------------------------------------------------
// Kernel C: main dequant GEMM. 344 N-strips (32 cols) x 4 K-chunks (1024)
// = 1376 blocks (~5.4/CU for TLP). LDS-staged W, double-buffered, BK=64/step.
// Pipeline fix vs round-3: per phase, the ISSUE ORDER is
//   xf-frags(step+1) [L2]  ->  q(step+3) [HBM]  ->  MFMA(step) -> DEQ(step+1)
// In-order vmcnt: MFMA's wait targets xf(step) (issued LAST PHASE, BEFORE the
// younger q loads) so the q prefetch queue is never drained; q gets ~2.5
// phases of HBM cover (3 register buffers). One effective vmem wait/phase.
// ---------------------------------------------------------------------------
__global__ __launch_bounds__(256, 4) void k_main(const int* __restrict__ qw,
                                                 const int* __restrict__ zr,
                                                 const float* __restrict__ sc,
                                                 const bf16_t* __restrict__ xf,
                                                 float* __restrict__ out) {
  const int nb = blockIdx.x % NSTRIPS;
  const int kc = blockIdx.x / NSTRIPS;  // 0..3
  const int o0 = nb * OCOLS;
  const int k0 = kc * 1024;

  __shared__ __align__(16) bf16_t wlds[2][OCOLS * WSTRIDE];  // 9216 B

  const int tid = threadIdx.x;
  const int w = tid >> 6;
  const int lane = tid & 63;
  const int oq = lane & 31;                     // staging column
  const int kq = w * 16 + ((lane >> 5) << 3);   // staging k-base (8 rows)
  const int ocol = o0 + oq;
  const int* qp = qw + (size_t)(k0 + kq) * N_OUT + ocol;

  // hoist all 8 groups' dequant params for this column
  float sf[8], nzs[8];
  {
    const int g0 = k0 >> 7;
#pragma unroll
    for (int g = 0; g < 8; ++g) {
      float s_ = sc[(size_t)(g0 + g) * N_OUT + ocol];
      int z_ = zr[(size_t)(g0 + g) * N_OUT + ocol];
      sf[g] = s_;
      nzs[g] = -(float)z_ * s_;
    }
  }

  const bf16_t* ap = xf + (size_t)lane * 8;
  const int aq = (lane >> 4) * 8;  // B-frag k-offset within 32-wide slice
  const int ol = lane & 15;

  int qr[3][8];        // 3-deep q prefetch ring (indices static after unroll)
  bf16x8 xfr[2][4];    // A-frag double buffer [step parity][mt*2+ks]
  f32x4 acc[2][2];
#pragma unroll
  for (int mt = 0; mt < 2; ++mt)
#pragma unroll
    for (int ot = 0; ot < 2; ++ot) acc[mt][ot] = (f32x4){0.f, 0.f, 0.f, 0.f};

#define LOAD_Q(S)                                                              \
  if ((S) < 16) {                                                              \
    const int* qn = qp + (size_t)(S) * 64 * N_OUT;                             \
    _Pragma("unroll") for (int j = 0; j < 8; ++j)                              \
        qr[(S) % 3][j] = qn[(size_t)j * N_OUT];                                \
  }

#define LOAD_XF(S)                                                             \
  if ((S) < 16) {                                                              \
    _Pragma("unroll") for (int mtl = 0; mtl < 2; ++mtl)                        \
        _Pragma("unroll") for (int ks = 0; ks < 2; ++ks)                       \
            xfr[(S)&1][mtl * 2 + ks] = *(const bf16x8*)(                       \
                ap + ((size_t)((2 * w + mtl) * 128 + kc * 32 + (S)*2 + ks)) *  \
                         512);                                                 \
  }

#define DEQ(S)                                                                 \
  if ((S) < 16) {                                                              \
    const int g_ = (S) >> 1;                                                   \
    bf16x8 wv;                                                                 \
    _Pragma("unroll") for (int j = 0; j < 8; ++j)                              \
        wv[j] = (bf16_t)fmaf((float)qr[(S) % 3][j], sf[g_], nzs[g_]);          \
    *(bf16x8*)&wlds[(S)&1][oq * WSTRIDE + kq] = wv;                            \
  }

#define MFMA(S)                                                                \
  {                                                                            \
    _Pragma("unroll") for (int ks = 0; ks < 2; ++ks) {                         \
      _Pragma("unroll") for (int ot = 0; ot < 2; ++ot) {                       \
        bf16x8 bfrag =                                                         \
            *(bf16x8*)&wlds[(S)&1][(ot * 16 + ol) * WSTRIDE + ks * 32 + aq];   \
        acc[0][ot] = __builtin_amdgcn_mfma_f32_16x16x32_bf16(                  \
            xfr[(S)&1][0 * 2 + ks], bfrag, acc[0][ot], 0, 0, 0);               \
        acc[1][ot] = __builtin_amdgcn_mfma_f32_16x16x32_bf16(                  \
            xfr[(S)&1][1 * 2 + ks], bfrag, acc[1][ot], 0, 0, 0);               \
      }                                                                        \
    }                                                                          \
  }

  // ---- preamble: q(0), xf(0), q(1), q(2); dequant step0 -> lds[0] ----
  LOAD_Q(0)
  LOAD_XF(0)
  LOAD_Q(1)
  LOAD_Q(2)
  DEQ(0)

#pragma unroll
  for (int s = 0; s < 16; ++s) {
    __syncthreads();
    LOAD_XF(s + 1)   // L2 frags for next phase — issued BEFORE new q loads
    LOAD_Q(s + 3)    // HBM prefetch, 3 buffers deep
    MFMA(s)          // waits only through xf(s) (issued last phase)
    DEQ(s + 1)       // q(s+1) already covered by the xf(s) wait
  }

#undef LOAD_Q
#undef LOAD_XF
#undef DEQ
#undef MFMA

  // epilogue: C/D layout col = lane&15, row = (lane>>4)*4 + r
#pragma unroll
  for (int mt = 0; mt < 2; ++mt) {
    const int m = w * 32 + mt * 16 + ((lane >> 4) << 2);
#pragma unroll
    for (int ot = 0; ot < 2; ++ot) {
      const int o = o0 + ot * 16 + ol;
#pragma unroll
      for (int r = 0; r < 4; ++r)
        unsafeAtomicAdd(&out[(size_t)(m + r) * N_OUT + o], acc[mt][ot][r]);
    }
  }
}

// ---------------------------------------------------------------------------
extern "C" void kernel_launch(void* const* d_in, const int* in_sizes, int n_in,
                              void* d_out, int out_size, void* d_ws, size_t ws_size,
                              hipStream_t stream) {
  const float* x = (const float*)d_in[0];
  const int* qw = (const int*)d_in[1];
  const int* zr = (const int*)d_in[2];
  const float* sc = (const float*)d_in[3];
  const float* loraA = (const float*)d_in[4];
  const float* loraB = (const float*)d_in[5];
  float* out = (float*)d_out;

  float* T = (float*)d_ws;                     // 128*16 fp32 = 8 KB
  bf16_t* xf = (bf16_t*)((char*)d_ws + 8192);  // 128*4096 bf16 = 1 MB (frag layout)

  k_prep<<<dim3(M_TOK), dim3(256), 0, stream>>>(x, loraA, T, xf);
  k_lora<<<dim3(M_TOK * 43), dim3(256), 0, stream>>>(T, loraB, out);
  k_main<<<dim3(NSTRIPS * 4), dim3(256), 0, stream>>>(qw, zr, sc, xf, out);
}

// Round 5
// 299.447 us; speedup vs baseline: 1.0059x; 1.0059x over previous
//
#include <hip/hip_runtime.h>
#include <hip/hip_bf16.h>

typedef __bf16 bf16_t;
typedef __bf16 bf16x8 __attribute__((ext_vector_type(8)));
typedef float f32x4 __attribute__((ext_vector_type(4)));

#define M_TOK 128
#define K_IN 4096
#define N_OUT 11008
#define R_LORA 16
#define SCALING 2.0f
#define NSTRIPS 344  // 32-col strips
#define OCOLS 32
#define WSTRIDE 72  // bf16 elems per o-row in LDS (144 B, 16B-aligned, odd quads)

// ---------------------------------------------------------------------------
// Kernel A: x (fp32) -> xf (bf16, MFMA-A-fragment-contiguous layout) in ws,
// and T = (x @ lora_A^T) * SCALING in ws.
// xf layout: slot(mt, ks, lane) holds 8 bf16 where mt=m>>4, ks=k>>5,
//   lane=((k>>3)&3)*16 + (m&15), j=k&7.  In k_main the A-frag for (mt,ks)
//   is ONE contiguous 1 KB wave read (16 B/lane), L2-resident.
// ---------------------------------------------------------------------------
__global__ __launch_bounds__(256) void k_prep(const float* __restrict__ x,
                                              const float* __restrict__ loraA,
                                              float* __restrict__ T,
                                              bf16_t* __restrict__ xf) {
  const int m = blockIdx.x;
  const int mt = m >> 4;
  const int ml = m & 15;
  __shared__ float xs[K_IN];
  const float4* xr = (const float4*)(x + (size_t)m * K_IN);
#pragma unroll
  for (int c0 = 0; c0 < 2; ++c0) {
    const int c = c0 * 256 + threadIdx.x;  // c = k>>3, 0..511
    float4 vA = xr[2 * c], vB = xr[2 * c + 1];
    ((float4*)xs)[2 * c] = vA;
    ((float4*)xs)[2 * c + 1] = vB;
    bf16x8 pv = {(bf16_t)vA.x, (bf16_t)vA.y, (bf16_t)vA.z, (bf16_t)vA.w,
                 (bf16_t)vB.x, (bf16_t)vB.y, (bf16_t)vB.z, (bf16_t)vB.w};
    const int ks = c >> 2;
    const int lq = (c & 3) * 16 + ml;
    *(bf16x8*)(xf + ((size_t)(mt * 128 + ks) * 64 + lq) * 8) = pv;
  }
  __syncthreads();
  const int w = threadIdx.x >> 6;
  const int lane = threadIdx.x & 63;
  float a0 = 0.f, a1 = 0.f, a2 = 0.f, a3 = 0.f;
  const float4* A0 = (const float4*)(loraA + (size_t)(w * 4 + 0) * K_IN);
  const float4* A1 = (const float4*)(loraA + (size_t)(w * 4 + 1) * K_IN);
  const float4* A2 = (const float4*)(loraA + (size_t)(w * 4 + 2) * K_IN);
  const float4* A3 = (const float4*)(loraA + (size_t)(w * 4 + 3) * K_IN);
  for (int i = lane; i < K_IN / 4; i += 64) {
    float4 xv = ((float4*)xs)[i];
    float4 v0 = A0[i], v1 = A1[i], v2 = A2[i], v3 = A3[i];
    a0 += xv.x * v0.x + xv.y * v0.y + xv.z * v0.z + xv.w * v0.w;
    a1 += xv.x * v1.x + xv.y * v1.y + xv.z * v1.z + xv.w * v1.w;
    a2 += xv.x * v2.x + xv.y * v2.y + xv.z * v2.z + xv.w * v2.w;
    a3 += xv.x * v3.x + xv.y * v3.y + xv.z * v3.z + xv.w * v3.w;
  }
#pragma unroll
  for (int off = 32; off; off >>= 1) {
    a0 += __shfl_down(a0, off);
    a1 += __shfl_down(a1, off);
    a2 += __shfl_down(a2, off);
    a3 += __shfl_down(a3, off);
  }
  if (lane == 0) {
    float* tm = T + m * R_LORA + w * 4;
    tm[0] = a0 * SCALING;
    tm[1] = a1 * SCALING;
    tm[2] = a2 * SCALING;
    tm[3] = a3 * SCALING;
  }
}

// ---------------------------------------------------------------------------
// Kernel B: out = T @ lora_B^T (full overwrite of d_out -> handles poison,
// and provides the base the dequant GEMM atomically accumulates onto).
// ---------------------------------------------------------------------------
__global__ __launch_bounds__(256) void k_lora(const float* __restrict__ T,
                                              const float* __restrict__ loraB,
                                              float* __restrict__ out) {
  const int b = blockIdx.x;
  const int m = b / 43;
  const int o = (b % 43) * 256 + threadIdx.x;
  const float* t = T + m * R_LORA;
  const float4* br = (const float4*)(loraB + (size_t)o * R_LORA);
  float4 b0 = br[0], b1 = br[1], b2 = br[2], b3 = br[3];
  float s = t[0] * b0.x + t[1] * b0.y + t[2] * b0.z + t[3] * b0.w +
            t[4] * b1.x + t[5] * b1.y + t[6] * b1.z + t[7] * b1.w +
            t[8] * b2.x + t[9] * b2.y + t[10] * b2.z + t[11] * b2.w +
            t[12] * b3.x + t[13] * b3.y + t[14] * b3.z + t[15] * b3.w;
  out[(size_t)m * N_OUT + o] = s;
}

// ---------------------------------------------------------------------------
// Kernel C: main dequant GEMM. 344 N-strips (32 cols) x 4 K-chunks (1024)
// = 1376 blocks (~5.4/CU). LDS-staged W, double-buffered, BK=64 per phase.
// THE FIX vs rounds 0-4: the phase barrier is a raw s_barrier preceded by
// lgkmcnt(0) ONLY (inline asm). __syncthreads() lowers to a full
// "s_waitcnt vmcnt(0) lgkmcnt(0); s_barrier" which drained the entire q/xf
// prefetch queue every phase — that was the structural 2x. q and xf land in
// private VGPRs; only the LDS (wlds) traffic needs barrier ordering, so
// vmcnt stays counted and the 3-deep q prefetch truly spans barriers:
//   issue order per phase:  xf(s+1) [L2] -> q(s+3) [HBM] -> MFMA(s) -> DEQ(s+1)
//   MFMA(s) waits on xf(s) (issued last phase, BEFORE q(s+2)/q(s+3)) so the
//   younger HBM loads keep ~2 full phases (~1000 cy) of flight.
// ---------------------------------------------------------------------------
__global__ __launch_bounds__(256, 4) void k_main(const int* __restrict__ qw,
                                                 const int* __restrict__ zr,
                                                 const float* __restrict__ sc,
                                                 const bf16_t* __restrict__ xf,
                                                 float* __restrict__ out) {
  const int nb = blockIdx.x % NSTRIPS;
  const int kc = blockIdx.x / NSTRIPS;  // 0..3
  const int o0 = nb * OCOLS;
  const int k0 = kc * 1024;

  __shared__ __align__(16) bf16_t wlds[2][OCOLS * WSTRIDE];  // 9216 B

  const int tid = threadIdx.x;
  const int w = tid >> 6;
  const int lane = tid & 63;
  const int oq = lane & 31;                     // staging column
  const int kq = w * 16 + ((lane >> 5) << 3);   // staging k-base (8 rows)
  const int ocol = o0 + oq;
  const int* qp = qw + (size_t)(k0 + kq) * N_OUT + ocol;

  // hoist all 8 groups' dequant params for this column
  float sf[8], nzs[8];
  {
    const int g0 = k0 >> 7;
#pragma unroll
    for (int g = 0; g < 8; ++g) {
      float s_ = sc[(size_t)(g0 + g) * N_OUT + ocol];
      int z_ = zr[(size_t)(g0 + g) * N_OUT + ocol];
      sf[g] = s_;
      nzs[g] = -(float)z_ * s_;
    }
  }

  const bf16_t* ap = xf + (size_t)lane * 8;
  const int aq = (lane >> 4) * 8;  // B-frag k-offset within 32-wide slice
  const int ol = lane & 15;

  int qr[3][8];        // 3-deep q prefetch ring (indices static after unroll)
  bf16x8 xfr[2][4];    // A-frag double buffer [step parity][mt*2+ks]
  f32x4 acc[2][2];
#pragma unroll
  for (int mt = 0; mt < 2; ++mt)
#pragma unroll
    for (int ot = 0; ot < 2; ++ot) acc[mt][ot] = (f32x4){0.f, 0.f, 0.f, 0.f};

#define LOAD_Q(S)                                                              \
  if ((S) < 16) {                                                              \
    const int* qn = qp + (size_t)(S) * 64 * N_OUT;                             \
    _Pragma("unroll") for (int j = 0; j < 8; ++j)                              \
        qr[(S) % 3][j] = qn[(size_t)j * N_OUT];                                \
  }

#define LOAD_XF(S)                                                             \
  if ((S) < 16) {                                                              \
    _Pragma("unroll") for (int mtl = 0; mtl < 2; ++mtl)                        \
        _Pragma("unroll") for (int ks = 0; ks < 2; ++ks)                       \
            xfr[(S)&1][mtl * 2 + ks] = *(const bf16x8*)(                       \
                ap + ((size_t)((2 * w + mtl) * 128 + kc * 32 + (S)*2 + ks)) *  \
                         512);                                                 \
  }

#define DEQ(S)                                                                 \
  if ((S) < 16) {                                                              \
    const int g_ = (S) >> 1;                                                   \
    bf16x8 wv;                                                                 \
    _Pragma("unroll") for (int j = 0; j < 8; ++j)                              \
        wv[j] = (bf16_t)fmaf((float)qr[(S) % 3][j], sf[g_], nzs[g_]);          \
    *(bf16x8*)&wlds[(S)&1][oq * WSTRIDE + kq] = wv;                            \
  }

#define MFMA(S)                                                                \
  {                                                                            \
    _Pragma("unroll") for (int ks = 0; ks < 2; ++ks) {                         \
      _Pragma("unroll") for (int ot = 0; ot < 2; ++ot) {                       \
        bf16x8 bfrag =                                                         \
            *(bf16x8*)&wlds[(S)&1][(ot * 16 + ol) * WSTRIDE + ks * 32 + aq];   \
        acc[0][ot] = __builtin_amdgcn_mfma_f32_16x16x32_bf16(                  \
            xfr[(S)&1][0 * 2 + ks], bfrag, acc[0][ot], 0, 0, 0);               \
        acc[1][ot] = __builtin_amdgcn_mfma_f32_16x16x32_bf16(                  \
            xfr[(S)&1][1 * 2 + ks], bfrag, acc[1][ot], 0, 0, 0);               \
      }                                                                        \
    }                                                                          \
  }

  // LDS-only barrier: drain our own ds ops (write visibility) then s_barrier.
  // Crucially does NOT wait vmcnt -> global prefetch stays in flight.
#define PHASE_BARRIER()                                                        \
  asm volatile("s_waitcnt lgkmcnt(0)\n\ts_barrier" ::: "memory");

  // ---- preamble: q(0), xf(0), q(1), q(2); dequant step0 -> lds[0] ----
  LOAD_Q(0)
  LOAD_XF(0)
  LOAD_Q(1)
  LOAD_Q(2)
  DEQ(0)

#pragma unroll
  for (int s = 0; s < 16; ++s) {
    PHASE_BARRIER()
    LOAD_XF(s + 1)   // L2 frags for next phase — issued BEFORE new q loads
    __builtin_amdgcn_sched_barrier(0);  // pin: xf issues precede q issues
    LOAD_Q(s + 3)    // HBM prefetch, 3 buffers deep (~2 phases of flight)
    MFMA(s)          // waits only through xf(s); q(s+2), q(s+3) stay in flight
    DEQ(s + 1)       // q(s+1) already drained by the xf(s) wait
  }

#undef LOAD_Q
#undef LOAD_XF
#undef DEQ
#undef MFMA
#undef PHASE_BARRIER

  // epilogue: C/D layout col = lane&15, row = (lane>>4)*4 + r
#pragma unroll
  for (int mt = 0; mt < 2; ++mt) {
    const int m = w * 32 + mt * 16 + ((lane >> 4) << 2);
#pragma unroll
    for (int ot = 0; ot < 2; ++ot) {
      const int o = o0 + ot * 16 + ol;
#pragma unroll
      for (int r = 0; r < 4; ++r)
        unsafeAtomicAdd(&out[(size_t)(m + r) * N_OUT + o], acc[mt][ot][r]);
    }
  }
}

// ---------------------------------------------------------------------------
extern "C" void kernel_launch(void* const* d_in, const int* in_sizes, int n_in,
                              void* d_out, int out_size, void* d_ws, size_t ws_size,
                              hipStream_t stream) {
  const float* x = (const float*)d_in[0];
  const int* qw = (const int*)d_in[1];
  const int* zr = (const int*)d_in[2];
  const float* sc = (const float*)d_in[3];
  const float* loraA = (const float*)d_in[4];
  const float* loraB = (const float*)d_in[5];
  float* out = (float*)d_out;

  float* T = (float*)d_ws;                     // 128*16 fp32 = 8 KB
  bf16_t* xf = (bf16_t*)((char*)d_ws + 8192);  // 128*4096 bf16 = 1 MB (frag layout)

  k_prep<<<dim3(M_TOK), dim3(256), 0, stream>>>(x, loraA, T, xf);
  k_lora<<<dim3(M_TOK * 43), dim3(256), 0, stream>>>(T, loraB, out);
  k_main<<<dim3(NSTRIPS * 4), dim3(256), 0, stream>>>(qw, zr, sc, xf, out);
}

// Round 7
// 296.306 us; speedup vs baseline: 1.0165x; 1.0106x over previous
//
#include <hip/hip_runtime.h>
#include <hip/hip_bf16.h>

typedef __bf16 bf16_t;
typedef __bf16 bf16x8 __attribute__((ext_vector_type(8)));
typedef float f32x4 __attribute__((ext_vector_type(4)));

#define M_TOK 128
#define K_IN 4096
#define N_OUT 11008
#define R_LORA 16
#define SCALING 2.0f
#define NSTRIPS 344  // 32-col strips
#define OCOLS 32
#define KC 2         // K-chunks: 2 (halves epilogue atomics vs 4)
#define KCHUNK 2048
#define NPHASE 32    // KCHUNK / 64
#define WSTRIDE 72   // bf16 elems per o-row in LDS (144 B, 16B-aligned, odd quads)

// ---------------------------------------------------------------------------
// Kernel A: x (fp32) -> xf (bf16, MFMA-A-fragment-contiguous layout) in ws,
// and T = (x @ lora_A^T) * SCALING in ws.
// xf layout: slot(mt, ks, lane) holds 8 bf16 where mt=m>>4, ks=k>>5,
//   lane=((k>>3)&3)*16 + (m&15), j=k&7.  In k_main the A-frag for (mt,ks)
//   is ONE contiguous 1 KB wave read (16 B/lane), L2-resident.
// ---------------------------------------------------------------------------
__global__ __launch_bounds__(256) void k_prep(const float* __restrict__ x,
                                              const float* __restrict__ loraA,
                                              float* __restrict__ T,
                                              bf16_t* __restrict__ xf) {
  const int m = blockIdx.x;
  const int mt = m >> 4;
  const int ml = m & 15;
  __shared__ float xs[K_IN];
  const float4* xr = (const float4*)(x + (size_t)m * K_IN);
#pragma unroll
  for (int c0 = 0; c0 < 2; ++c0) {
    const int c = c0 * 256 + threadIdx.x;  // c = k>>3, 0..511
    float4 vA = xr[2 * c], vB = xr[2 * c + 1];
    ((float4*)xs)[2 * c] = vA;
    ((float4*)xs)[2 * c + 1] = vB;
    bf16x8 pv = {(bf16_t)vA.x, (bf16_t)vA.y, (bf16_t)vA.z, (bf16_t)vA.w,
                 (bf16_t)vB.x, (bf16_t)vB.y, (bf16_t)vB.z, (bf16_t)vB.w};
    const int ks = c >> 2;
    const int lq = (c & 3) * 16 + ml;
    *(bf16x8*)(xf + ((size_t)(mt * 128 + ks) * 64 + lq) * 8) = pv;
  }
  __syncthreads();
  const int w = threadIdx.x >> 6;
  const int lane = threadIdx.x & 63;
  float a0 = 0.f, a1 = 0.f, a2 = 0.f, a3 = 0.f;
  const float4* A0 = (const float4*)(loraA + (size_t)(w * 4 + 0) * K_IN);
  const float4* A1 = (const float4*)(loraA + (size_t)(w * 4 + 1) * K_IN);
  const float4* A2 = (const float4*)(loraA + (size_t)(w * 4 + 2) * K_IN);
  const float4* A3 = (const float4*)(loraA + (size_t)(w * 4 + 3) * K_IN);
  for (int i = lane; i < K_IN / 4; i += 64) {
    float4 xv = ((float4*)xs)[i];
    float4 v0 = A0[i], v1 = A1[i], v2 = A2[i], v3 = A3[i];
    a0 += xv.x * v0.x + xv.y * v0.y + xv.z * v0.z + xv.w * v0.w;
    a1 += xv.x * v1.x + xv.y * v1.y + xv.z * v1.z + xv.w * v1.w;
    a2 += xv.x * v2.x + xv.y * v2.y + xv.z * v2.z + xv.w * v2.w;
    a3 += xv.x * v3.x + xv.y * v3.y + xv.z * v3.z + xv.w * v3.w;
  }
#pragma unroll
  for (int off = 32; off; off >>= 1) {
    a0 += __shfl_down(a0, off);
    a1 += __shfl_down(a1, off);
    a2 += __shfl_down(a2, off);
    a3 += __shfl_down(a3, off);
  }
  if (lane == 0) {
    float* tm = T + m * R_LORA + w * 4;
    tm[0] = a0 * SCALING;
    tm[1] = a1 * SCALING;
    tm[2] = a2 * SCALING;
    tm[3] = a3 * SCALING;
  }
}

// ---------------------------------------------------------------------------
// Kernel B: out = T @ lora_B^T (full overwrite of d_out -> handles poison,
// and provides the base the dequant GEMM atomically accumulates onto).
// ---------------------------------------------------------------------------
__global__ __launch_bounds__(256) void k_lora(const float* __restrict__ T,
                                              const float* __restrict__ loraB,
                                              float* __restrict__ out) {
  const int b = blockIdx.x;
  const int m = b / 43;
  const int o = (b % 43) * 256 + threadIdx.x;
  const float* t = T + m * R_LORA;
  const float4* br = (const float4*)(loraB + (size_t)o * R_LORA);
  float4 b0 = br[0], b1 = br[1], b2 = br[2], b3 = br[3];
  float s = t[0] * b0.x + t[1] * b0.y + t[2] * b0.z + t[3] * b0.w +
            t[4] * b1.x + t[5] * b1.y + t[6] * b1.z + t[7] * b1.w +
            t[8] * b2.x + t[9] * b2.y + t[10] * b2.z + t[11] * b2.w +
            t[12] * b3.x + t[13] * b3.y + t[14] * b3.z + t[15] * b3.w;
  out[(size_t)m * N_OUT + o] = s;
}

// ---------------------------------------------------------------------------
// Kernel C: main dequant GEMM. 344 N-strips (32 cols) x 2 K-chunks (2048)
// = 688 blocks. LDS-staged W, double-buffered, BK=64 per phase, 32 phases.
// EXACT round-5 pipeline (passed): lgkm-only phase barrier (keeps global
// prefetch in flight across barriers), 3-deep q register ring, xf-before-q
// issue order. ONLY change vs round-5: KC 4 -> 2, halving the epilogue's
// fp32 atomic count (5.6M -> 2.8M); dequant params stay in REGISTERS
// (sf[16]/nzs[16], +16 VGPR). launch_bounds (256,3): grid gives only
// ~2.7 blocks/CU anyway (grid-limited), and 3 avoids any scratch spill
// from the larger param arrays.
// ---------------------------------------------------------------------------
__global__ __launch_bounds__(256, 3) void k_main(const int* __restrict__ qw,
                                                 const int* __restrict__ zr,
                                                 const float* __restrict__ sc,
                                                 const bf16_t* __restrict__ xf,
                                                 float* __restrict__ out) {
  const int nb = blockIdx.x % NSTRIPS;
  const int kc = blockIdx.x / NSTRIPS;  // 0..1
  const int o0 = nb * OCOLS;
  const int k0 = kc * KCHUNK;

  __shared__ __align__(16) bf16_t wlds[2][OCOLS * WSTRIDE];  // 9216 B

  const int tid = threadIdx.x;
  const int w = tid >> 6;
  const int lane = tid & 63;
  const int oq = lane & 31;                     // staging column
  const int kq = w * 16 + ((lane >> 5) << 3);   // staging k-base (8 rows)
  const int ocol = o0 + oq;
  const int* qp = qw + (size_t)(k0 + kq) * N_OUT + ocol;

  // hoist all 16 groups' dequant params for this column (registers, as R5)
  float sf[16], nzs[16];
  {
    const int g0 = k0 >> 7;  // kc*16
#pragma unroll
    for (int g = 0; g < 16; ++g) {
      float s_ = sc[(size_t)(g0 + g) * N_OUT + ocol];
      int z_ = zr[(size_t)(g0 + g) * N_OUT + ocol];
      sf[g] = s_;
      nzs[g] = -(float)z_ * s_;
    }
  }

  const bf16_t* ap = xf + (size_t)lane * 8;
  const int aq = (lane >> 4) * 8;  // B-frag k-offset within 32-wide slice
  const int ol = lane & 15;

  int qr[3][8];        // 3-deep q prefetch ring (indices static after unroll)
  bf16x8 xfr[2][4];    // A-frag double buffer [step parity][mt*2+ks]
  f32x4 acc[2][2];
#pragma unroll
  for (int mt = 0; mt < 2; ++mt)
#pragma unroll
    for (int ot = 0; ot < 2; ++ot) acc[mt][ot] = (f32x4){0.f, 0.f, 0.f, 0.f};

#define LOAD_Q(S)                                                              \
  if ((S) < NPHASE) {                                                          \
    const int* qn = qp + (size_t)(S) * 64 * N_OUT;                             \
    _Pragma("unroll") for (int j = 0; j < 8; ++j)                              \
        qr[(S) % 3][j] = qn[(size_t)j * N_OUT];                                \
  }

#define LOAD_XF(S)                                                             \
  if ((S) < NPHASE) {                                                          \
    _Pragma("unroll") for (int mtl = 0; mtl < 2; ++mtl)                        \
        _Pragma("unroll") for (int ks = 0; ks < 2; ++ks)                       \
            xfr[(S)&1][mtl * 2 + ks] = *(const bf16x8*)(                       \
                ap + ((size_t)((2 * w + mtl) * 128 + kc * 64 + (S)*2 + ks)) *  \
                         512);                                                 \
  }

#define DEQ(S)                                                                 \
  if ((S) < NPHASE) {                                                          \
    const int g_ = (S) >> 1;                                                   \
    bf16x8 wv;                                                                 \
    _Pragma("unroll") for (int j = 0; j < 8; ++j)                              \
        wv[j] = (bf16_t)fmaf((float)qr[(S) % 3][j], sf[g_], nzs[g_]);          \
    *(bf16x8*)&wlds[(S)&1][oq * WSTRIDE + kq] = wv;                            \
  }

#define MFMA(S)                                                                \
  {                                                                            \
    _Pragma("unroll") for (int ks = 0; ks < 2; ++ks) {                         \
      _Pragma("unroll") for (int ot = 0; ot < 2; ++ot) {                       \
        bf16x8 bfrag =                                                         \
            *(bf16x8*)&wlds[(S)&1][(ot * 16 + ol) * WSTRIDE + ks * 32 + aq];   \
        acc[0][ot] = __builtin_amdgcn_mfma_f32_16x16x32_bf16(                  \
            xfr[(S)&1][0 * 2 + ks], bfrag, acc[0][ot], 0, 0, 0);               \
        acc[1][ot] = __builtin_amdgcn_mfma_f32_16x16x32_bf16(                  \
            xfr[(S)&1][1 * 2 + ks], bfrag, acc[1][ot], 0, 0, 0);               \
      }                                                                        \
    }                                                                          \
  }

  // LDS-only barrier: drain our own ds ops (write visibility) then s_barrier.
  // Crucially does NOT wait vmcnt -> global prefetch stays in flight.
#define PHASE_BARRIER()                                                        \
  asm volatile("s_waitcnt lgkmcnt(0)\n\ts_barrier" ::: "memory");

  // ---- preamble: q(0), xf(0), q(1), q(2); dequant step0 -> lds[0] ----
  LOAD_Q(0)
  LOAD_XF(0)
  LOAD_Q(1)
  LOAD_Q(2)
  DEQ(0)

#pragma unroll
  for (int s = 0; s < NPHASE; ++s) {
    PHASE_BARRIER()
    LOAD_XF(s + 1)   // L2 frags for next phase — issued BEFORE new q loads
    __builtin_amdgcn_sched_barrier(0);  // pin: xf issues precede q issues
    LOAD_Q(s + 3)    // HBM prefetch, 3 buffers deep (~2 phases of flight)
    MFMA(s)          // waits only through xf(s); q(s+2), q(s+3) stay in flight
    DEQ(s + 1)       // q(s+1) already drained by the xf(s) wait
  }

#undef LOAD_Q
#undef LOAD_XF
#undef DEQ
#undef MFMA
#undef PHASE_BARRIER

  // epilogue: C/D layout col = lane&15, row = (lane>>4)*4 + r
#pragma unroll
  for (int mt = 0; mt < 2; ++mt) {
    const int m = w * 32 + mt * 16 + ((lane >> 4) << 2);
#pragma unroll
    for (int ot = 0; ot < 2; ++ot) {
      const int o = o0 + ot * 16 + ol;
#pragma unroll
      for (int r = 0; r < 4; ++r)
        unsafeAtomicAdd(&out[(size_t)(m + r) * N_OUT + o], acc[mt][ot][r]);
    }
  }
}

// ---------------------------------------------------------------------------
extern "C" void kernel_launch(void* const* d_in, const int* in_sizes, int n_in,
                              void* d_out, int out_size, void* d_ws, size_t ws_size,
                              hipStream_t stream) {
  const float* x = (const float*)d_in[0];
  const int* qw = (const int*)d_in[1];
  const int* zr = (const int*)d_in[2];
  const float* sc = (const float*)d_in[3];
  const float* loraA = (const float*)d_in[4];
  const float* loraB = (const float*)d_in[5];
  float* out = (float*)d_out;

  float* T = (float*)d_ws;                     // 128*16 fp32 = 8 KB
  bf16_t* xf = (bf16_t*)((char*)d_ws + 8192);  // 128*4096 bf16 = 1 MB (frag layout)

  k_prep<<<dim3(M_TOK), dim3(256), 0, stream>>>(x, loraA, T, xf);
  k_lora<<<dim3(M_TOK * 43), dim3(256), 0, stream>>>(T, loraB, out);
  k_main<<<dim3(NSTRIPS * KC), dim3(256), 0, stream>>>(qw, zr, sc, xf, out);
}